// Round 3
// baseline (588.340 us; speedup 1.0000x reference)
//
#include <hip/hip_runtime.h>
#include <cmath>

// ConvLSTM2D forward, bf16 MFMA implicit GEMM, R8: barrier-free K-loop, B in regs.
// B=8, T=16, H=W=96, Cin=8, F=64 (4F=256 gates), 3x3 SAME, 16 sequential steps.
// Per step GEMM: M=73728, N=256, K=672 (21 K-steps of 32: 18 h + 3 packed x).
// R8 vs R7 (R7 still LDS-pipe + barrier bound: 84/123 ds_reads were B, plus 21
// lockstep barriers/step protecting the LDS slab ring):
//  - B fragments load global->VGPR directly (L1/L2-resident 84KB/block stream),
//    double-buffered in registers; bslab LDS + ALL K-loop barriers removed.
//  - LDS = halo only (36KB): hplanes [plane=kh*4+q][256pos][8ch] + xplane,
//    staged via global_load_lds (per-lane gather src, lane-linear dest),
//    one __syncthreads total; K-loop reads are A-fragments only (39/wave/step).
//  - 4 blocks/CU (16 waves): LDS 36.9KB, VGPR capped 128 via launch_bounds.
// Expected regime: MFMA-pipe-bound (~12.2us/CU/step floor).

#define HTOT 96
#define WTOT 96
#define CINX 8
#define FF   64
#define G4   256
#define BB   8
#define TT   16
#define NPOS (BB*HTOT*WTOT)        // 73728 global positions

typedef __attribute__((ext_vector_type(8))) short short8;   // 8 bf16 = 4 VGPRs
typedef __attribute__((ext_vector_type(4))) float floatx4;

union U16 { uint4 u; short8 s; };

__device__ __forceinline__ float hsig(float z) {
    return fminf(fmaxf(0.2f * z + 0.5f, 0.f), 1.f);
}

__device__ __forceinline__ float ftanh(float x) {
    float e = __expf(-2.f * fabsf(x));
    float t = (1.f - e) / (1.f + e);
    return copysignf(t, x);
}

__device__ __forceinline__ ushort f2bf(float f) {            // RNE fp32->bf16
    unsigned u = __float_as_uint(f);
    u = (u + 0x7fff + ((u >> 16) & 1)) >> 16;
    return (ushort)u;
}

// async 16B global->LDS; global source is per-lane, LDS dest = uniform base + lane*16
__device__ __forceinline__ void async16(const void* g, void* l) {
    __builtin_amdgcn_global_load_lds(
        (const __attribute__((address_space(1))) void*)g,
        (__attribute__((address_space(3))) void*)l, 16, 0, 0);
}

// ---- prep: x fp32 -> bf16 (all T at once), layout [b,t,y,x,8] ----
__global__ __launch_bounds__(256) void conv_x_bf16(const float* __restrict__ x,
                                                   ushort* __restrict__ xbf, int n4) {
    int i = blockIdx.x * 256 + threadIdx.x;
    if (i >= n4) return;
    float4 v = ((const float4*)x)[i];
    ushort4 o;
    o.x = f2bf(v.x); o.y = f2bf(v.y); o.z = f2bf(v.z); o.w = f2bf(v.w);
    ((ushort4*)xbf)[i] = o;
}

// ---- prep: weights -> per-slice slab stream, slab s order = dx*6 + kh*3 + dy ----
// Bp[(slice*21+s)*256 + g*64 + lane] (16B units); lane(q,col) holds B rows q*8..q*8+7
__global__ __launch_bounds__(256) void prep_w(const float* __restrict__ Wx,
                                              const float* __restrict__ Wh,
                                              ushort* __restrict__ Bp) {
    int idx = blockIdx.x * 256 + threadIdx.x;
    if (idx >= 4 * 21 * 256) return;                 // 21504
    int lane = idx & 63;
    int g = (idx >> 6) & 3;
    int rest = idx >> 8;                             // slice*21 + s
    int s = rest % 21, slice = rest / 21;
    int q = lane >> 4, col = lane & 15;
    int n = g * 64 + slice * 16 + col;
    ushort o[8];
    if (s < 18) {
        int dxw = s / 6, rem = s - 6 * dxw;
        int khw = rem / 3, dyw = rem - 3 * khw;
        int tap = dyw * 3 + dxw;
        int cbase = khw * 32 + q * 8;
        #pragma unroll
        for (int j = 0; j < 8; ++j)
            o[j] = f2bf(Wh[((size_t)tap * FF + cbase + j) * G4 + n]);
    } else {
        int tap = (s - 18) * 4 + q;                  // packed x-taps; >8 -> zero pad
        #pragma unroll
        for (int j = 0; j < 8; ++j)
            o[j] = (tap < 9) ? f2bf(Wx[((size_t)tap * CINX + j) * G4 + n]) : (ushort)0;
    }
    U16 u;
    #pragma unroll
    for (int j = 0; j < 8; ++j) ((ushort*)&u)[j] = o[j];
    ((uint4*)Bp)[idx] = u.u;
}

// ---- main step kernel ----
__global__ __launch_bounds__(256, 4) void convlstm_mfma(
    const ushort* __restrict__ xbf, int t,
    const ushort* __restrict__ hS_in,     // [slice][pos][16] bf16
    ushort* __restrict__ hS_out,
    float* __restrict__ cS,               // [slice][pos][16] fp32
    const ushort* __restrict__ Bp,
    const float* __restrict__ bias,
    const uint4* __restrict__ zpad,       // 64B of zeros for OOB halo lanes
    float* __restrict__ out, int last)
{
    // channel-plane halo: plane p = kh*4+q holds channels p*8..p*8+7 for 256 pos
    __shared__ __align__(16) ushort hplanes[8 * 2048];   // 8 x 4KB = 32KB
    __shared__ __align__(16) ushort xplane[2048];        // 4KB (x halo, 8ch/pos)

    const int tid = threadIdx.x;
    const int x0 = blockIdx.x * 16, y0 = blockIdx.y * 12;
    const int bb = blockIdx.z >> 2, slice = blockIdx.z & 3;

    const int w = tid >> 6, lane = tid & 63, q = lane >> 4, col = lane & 15;
    const int rowb = w * 3;                    // wave rows rowb..rowb+2 (of 12)

    // per-lane B pointer: fragment (s,g) at gB[s*256 + g*64]
    const uint4* gB = (const uint4*)Bp + (size_t)(slice * 21) * 256 + lane;

    // stage 14x18 halo (pos = tid, 0..251 valid; 252..255 loaded but never read)
    {
        int py = tid / 18, px = tid - py * 18;
        int gy = y0 - 1 + py, gx = x0 - 1 + px;
        bool ok = (gy >= 0 && gy < HTOT && gx >= 0 && gx < WTOT);
        int gyc = gy < 0 ? 0 : (gy > HTOT - 1 ? HTOT - 1 : gy);
        int gxc = gx < 0 ? 0 : (gx > WTOT - 1 ? WTOT - 1 : gx);
        size_t gpos = ((size_t)bb * HTOT + gyc) * WTOT + gxc;
        #pragma unroll
        for (int p = 0; p < 8; ++p) {
            const void* src = ok
                ? (const void*)(hS_in + ((size_t)(p >> 1) * NPOS + gpos) * 16 + (p & 1) * 8)
                : (const void*)zpad;
            async16(src, hplanes + p * 2048 + tid * 8);
        }
        const void* sxp = ok
            ? (const void*)(xbf + ((((size_t)bb * TT + t) * HTOT + gyc) * WTOT + gxc) * CINX)
            : (const void*)zpad;
        async16(sxp, xplane + tid * 8);
    }

    const ushort* hA = hplanes + q * 2048 + (rowb * 18 + col) * 8;  // per-lane base

    // preload B slab 0 into registers while halo staging is in flight
    U16 bbuf[2][4];
    #pragma unroll
    for (int g = 0; g < 4; ++g) bbuf[0][g].u = gB[g * 64];

    floatx4 acc[3][4];
    #pragma unroll
    for (int g = 0; g < 4; ++g) {
        float bv = bias[g * 64 + slice * 16 + col];
        acc[0][g] = (floatx4){bv, bv, bv, bv};
        acc[1][g] = (floatx4){bv, bv, bv, bv};
        acc[2][g] = (floatx4){bv, bv, bv, bv};
    }

    __syncthreads();   // drains halo async loads; only barrier in the kernel

    // ---- K-loop: s = dx*6 + kh*3 + dy; barrier-free; B double-buffered in regs ----
    U16 aw[4];
    #pragma unroll
    for (int dx = 0; dx < 3; ++dx) {
        #pragma unroll
        for (int kh = 0; kh < 2; ++kh) {
            #pragma unroll
            for (int j = 0; j < 3; ++j)        // prime rows 0..2 -> slots 0..2
                aw[j].u = *(const uint4*)(hA + kh * 8192 + j * 144 + dx * 8);
            #pragma unroll
            for (int dy = 0; dy < 3; ++dy) {
                const int s = dx * 6 + kh * 3 + dy;
                #pragma unroll
                for (int g = 0; g < 4; ++g)    // prefetch next slab into other buffer
                    bbuf[(s + 1) & 1][g].u = gB[(s + 1) * 256 + g * 64];
                if (dy)                         // slide: row dy+2 -> slot (dy+2)&3
                    aw[(dy + 2) & 3].u = *(const uint4*)(hA + kh * 8192 + (dy + 2) * 144 + dx * 8);
                #pragma unroll
                for (int g = 0; g < 4; ++g)
                    #pragma unroll
                    for (int mt = 0; mt < 3; ++mt)
                        acc[mt][g] = __builtin_amdgcn_mfma_f32_16x16x32_bf16(
                            aw[(mt + dy) & 3].s, bbuf[s & 1][g].s, acc[mt][g], 0, 0, 0);
            }
        }
    }
    // ---- x phase: s = 18,19,20 ----
    #pragma unroll
    for (int sx = 0; sx < 3; ++sx) {
        const int s = 18 + sx;
        int tap = sx * 4 + q; if (tap > 8) tap = 8;   // padded taps: B rows are 0
        int dyq = tap / 3, dxq = tap - 3 * dyq;
        const ushort* xA = xplane + ((rowb + dyq) * 18 + col + dxq) * 8;
        if (sx < 2) {
            #pragma unroll
            for (int g = 0; g < 4; ++g)
                bbuf[(s + 1) & 1][g].u = gB[(s + 1) * 256 + g * 64];
        }
        U16 a4[3];
        #pragma unroll
        for (int mt = 0; mt < 3; ++mt)
            a4[mt].u = *(const uint4*)(xA + mt * 144);
        #pragma unroll
        for (int g = 0; g < 4; ++g)
            #pragma unroll
            for (int mt = 0; mt < 3; ++mt)
                acc[mt][g] = __builtin_amdgcn_mfma_f32_16x16x32_bf16(
                    a4[mt].s, bbuf[s & 1][g].s, acc[mt][g], 0, 0, 0);
    }

    // ---- epilogue: gates fused in-register; contiguous slice-major writes ----
    #pragma unroll
    for (int mt = 0; mt < 3; ++mt) {
        int gy = y0 + rowb + mt;
        #pragma unroll
        for (int r = 0; r < 4; ++r) {
            int gx = x0 + q * 4 + r;
            size_t gpos = ((size_t)bb * HTOT + gy) * WTOT + gx;
            size_t idx = ((size_t)slice * NPOS + gpos) * 16 + col;
            float zi = acc[mt][0][r], zf = acc[mt][1][r];
            float zg = acc[mt][2][r], zo = acc[mt][3][r];
            float cn = hsig(zf) * cS[idx] + hsig(zi) * ftanh(zg);
            cS[idx] = cn;
            float hn = hsig(zo) * ftanh(cn);
            hS_out[idx] = f2bf(hn);
            if (last) out[gpos * 64 + slice * 16 + col] = hn;
        }
    }
}

extern "C" void kernel_launch(void* const* d_in, const int* in_sizes, int n_in,
                              void* d_out, int out_size, void* d_ws, size_t ws_size,
                              hipStream_t stream) {
    const float* x  = (const float*)d_in[0];
    const float* Wx = (const float*)d_in[1];
    const float* Wh = (const float*)d_in[2];
    const float* b  = (const float*)d_in[3];

    const size_t NX = (size_t)BB * TT * HTOT * WTOT * CINX;  // 9,437,184
    const size_t NH = (size_t)NPOS * FF;                     // 4,718,592

    char* ws = (char*)d_ws;
    ushort* xbf = (ushort*)ws;                  ws += NX * 2;            // 18.9 MB
    ushort* hS0 = (ushort*)ws;                  ws += NH * 2;            //  9.4 MB
    ushort* hS1 = (ushort*)ws;                  ws += NH * 2;            //  9.4 MB
    float*  cS  = (float*)ws;                   ws += NH * 4;            // 18.9 MB
    ushort* Bp  = (ushort*)ws;                  ws += (size_t)4*21*256*16; // 344 KB
    uint4*  zpad = (uint4*)ws;                                           // 64 B zeros

    hipMemsetAsync(hS0, 0, NH * 2, stream);
    hipMemsetAsync(cS,  0, NH * 4, stream);
    hipMemsetAsync(zpad, 0, 64, stream);

    conv_x_bf16<<<(int)((NX / 4 + 255) / 256), 256, 0, stream>>>(x, xbf, (int)(NX / 4));
    prep_w<<<(4 * 21 * 256 + 255) / 256, 256, 0, stream>>>(Wx, Wh, Bp);

    dim3 grid(WTOT / 16, HTOT / 12, BB * 4);
    for (int t = 0; t < TT; ++t) {
        const ushort* hin = (t & 1) ? hS1 : hS0;
        ushort* hout      = (t & 1) ? hS0 : hS1;
        convlstm_mfma<<<grid, 256, 0, stream>>>(xbf, t, hin, hout, cS, Bp, b, zpad,
                                                (float*)d_out, t == TT - 1);
    }
}